// Round 5
// baseline (255.982 us; speedup 1.0000x reference)
//
#include <hip/hip_runtime.h>
#include <math.h>
#include <stddef.h>

#define NN    4096
#define BATCH 2
#define CD    64
#define KSEL  24
#define RAD2  0.2025f     // 0.45^2
#define LCAP  224
#define NBLK  512         // even; half the blocks per batch; == 2 blocks/CU resident
#define WPB   4

// ---- prep: transpose td & sd to (B,N,C); addj = clamp(log tgt_match,-20) - 0.1*tu;
// ---- zero the work-stealing counters ----
__global__ __launch_bounds__(256)
void prep_all(const float* __restrict__ td, const float* __restrict__ sd,
              const float* __restrict__ tml, const float* __restrict__ tu,
              float* __restrict__ tdT, float* __restrict__ sdT,
              float* __restrict__ addj, int* __restrict__ gcnt) {
  __shared__ float tile[64][65];
  int blk = blockIdx.x;
  if (blk < 256) {
    const float* src = (blk < 128) ? td  : sd;
    float*       dst = (blk < 128) ? tdT : sdT;
    int lb = blk & 127;
    int b  = lb >> 6;
    int j0 = (lb & 63) << 6;
    int jl = threadIdx.x & 63;
    int cq = threadIdx.x >> 6;
    const float* srcp = src + (size_t)b * CD * NN;
#pragma unroll
    for (int r = 0; r < 16; ++r) {
      int c = r * 4 + cq;
      tile[c][jl] = srcp[(size_t)c * NN + j0 + jl];
    }
    __syncthreads();
    float* dstp = dst + (size_t)b * NN * CD;
#pragma unroll
    for (int r = 0; r < 16; ++r) {
      int j = r * 4 + cq;
      dstp[(size_t)(j0 + j) * CD + jl] = tile[jl][j];
    }
  } else {
    int idx = (blk - 256) * 256 + threadIdx.x;
    if (idx < BATCH * NN) {
      int b = idx >> 12, j = idx & (NN - 1);
      float l0 = tml[(size_t)b * 2 * NN + j];
      float l1 = tml[(size_t)b * 2 * NN + NN + j];
      float x  = l1 - l0;
      float sp = fmaxf(x, 0.0f) + log1pf(expf(-fabsf(x)));
      addj[idx] = fmaxf(-sp, -20.0f) - 0.1f * tu[idx];
    }
    if (idx < BATCH) gcnt[idx] = 0;
  }
}

// ---- main: tc staged in LDS once per block; waves steal rows; no per-row barriers ----
__global__ __launch_bounds__(256, 2)
void matcher_main(const float* __restrict__ sc, const float* __restrict__ tc,
                  const float* __restrict__ sd, const float* __restrict__ td,
                  const float* __restrict__ tdT, const float* __restrict__ sdT,
                  const float* __restrict__ addj,
                  const float* __restrict__ tml, const float* __restrict__ tu,
                  const float* __restrict__ sml, int* __restrict__ gcnt,
                  float* __restrict__ oexp, float* __restrict__ odisp,
                  float* __restrict__ oprob, float* __restrict__ oconf,
                  float* __restrict__ oent, float* __restrict__ osrc) {
  __shared__ __align__(16) float ltc[3 * NN];     // 48 KB: this batch's tgt coords
  __shared__ __align__(16) float sdp[WPB][CD];
  __shared__ __align__(16) int2  list[WPB][LCAP];

  const int tid  = threadIdx.x;
  const int w    = tid >> 6;
  const int lane = tid & 63;
  const int b    = blockIdx.x & 1;

  // stage tc for batch b (once per block)
  {
    const float4* g4 = (const float4*)(tc + (size_t)b * 3 * NN);
    float4* l4 = (float4*)ltc;
#pragma unroll
    for (int q = 0; q < 12; ++q) l4[q * 256 + tid] = g4[q * 256 + tid];
  }
  __syncthreads();   // only block-wide barrier

  const float4* lx = (const float4*)ltc;
  const float4* ly = (const float4*)(ltc + NN);
  const float4* lz = (const float4*)(ltc + 2 * NN);
  const float* tdb = tdT ? tdT + (size_t)b * NN * CD : nullptr;
  const float* scb = sc + (size_t)b * 3 * NN;

  int it = 0;
  for (;;) {
    int row_l;
    if (gcnt) {
      if (lane == 0) row_l = atomicAdd(&gcnt[b], 1);
      row_l = __shfl(row_l, 0);
    } else {
      row_l = ((blockIdx.x >> 1) * WPB + w) + it * ((NBLK / 2) * WPB);
      ++it;
    }
    if (row_l >= NN) break;
    const int i   = row_l;
    const int row = b * NN + i;

    // source point comes from src_canonical (NOT the staged target coords!)
    const float s0 = scb[i], s1 = scb[NN + i], s2 = scb[2 * NN + i];
    sdp[w][lane] = sdT ? sdT[((size_t)b * NN + i) * CD + lane]
                       : sd[(size_t)b * CD * NN + (size_t)lane * NN + i];

    // ---- single pass: d2 -> registers (bits), count radius hits, zero-fill probs ----
    unsigned d2b[64];
    int crad = 0;
    float4* prow4 = (float4*)(oprob + (size_t)row * NN);
    float4 z4; z4.x = z4.y = z4.z = z4.w = 0.0f;
#pragma unroll
    for (int k = 0; k < 16; ++k) {
      int g = (k << 6) + lane;
      float4 X = lx[g], Y = ly[g], Z = lz[g];
      prow4[g] = z4;
      float xs[4] = {X.x, X.y, X.z, X.w};
      float ys[4] = {Y.x, Y.y, Y.z, Y.w};
      float zs[4] = {Z.x, Z.y, Z.z, Z.w};
#pragma unroll
      for (int r = 0; r < 4; ++r) {
        float dx = xs[r] - s0, dy = ys[r] - s1, dz = zs[r] - s2;
        float d2 = fmaxf(__fmaf_rn(dx, dx, __fmaf_rn(dy, dy, dz * dz)), 1e-12f);
        d2b[4 * k + r] = __float_as_uint(d2);
        crad += (d2 <= RAD2);
      }
    }
#pragma unroll
    for (int off = 32; off; off >>= 1) crad += __shfl_xor(crad, off);

    auto countle = [&](unsigned mb) -> int {
      int c = 0;
#pragma unroll
      for (int m = 0; m < 64; ++m) c += (d2b[m] <= mb);
#pragma unroll
      for (int off = 32; off; off >>= 1) c += __shfl_xor(c, off);
      return c;
    };

    // ---- threshold: radius if >=24 inside; else exact 24th via bit search ----
    unsigned thr;
    if (crad >= KSEL) {
      thr = __float_as_uint(RAD2);
    } else {
      unsigned lo = __float_as_uint(RAD2);
      unsigned hi = 0x7f800000u;
      int c = crad;
      float t = RAD2;
#pragma unroll 1
      for (int p = 0; p < 6; ++p) {
        t *= 4.0f;
        unsigned tb = __float_as_uint(t);
        c = countle(tb);
        if (c >= KSEL) { hi = tb; break; }
        lo = tb;
      }
      if (c == KSEL) {
        thr = hi;     // count exactly 24 below hi -> exact allowed set
      } else {
#pragma unroll 1
        while (lo + 1u < hi) {
          unsigned mid = (lo + hi) >> 1;
          int cm = countle(mid);
          if (cm >= KSEL) { hi = mid; if (cm == KSEL) break; }
          else lo = mid;
        }
        thr = hi;
      }
    }

    // ---- compact allowed (j, d2bits) via ballot prefix (no atomics) ----
    int base = 0;
#pragma unroll
    for (int m = 0; m < 64; ++m) {
      bool p = (d2b[m] <= thr);
      unsigned long long mk = __ballot(p);
      if (p) {
        int idx = base + (int)__popcll(mk & ((1ull << lane) - 1ull));
        int j = ((m >> 2) << 8) + (lane << 2) + (m & 3);
        if (idx < LCAP) list[w][idx] = make_int2(j, (int)d2b[m]);
      }
      base += (int)__popcll(mk);
    }
    const int na = base < LCAP ? base : LCAP;

    // ---- scores ----
    const float4* sp4 = (const float4*)sdp[w];
    float mloc = -1e30f;
    for (int e = lane; e < na; e += 64) {
      int2 en = list[w][e];
      int j = en.x;
      float d2 = __uint_as_float((unsigned)en.y);
      float sim = 0.0f;
      if (tdb) {
        const float4* trow = (const float4*)(tdb + (size_t)j * CD);
#pragma unroll
        for (int q = 0; q < CD / 4; ++q) {
          float4 a = sp4[q], t4 = trow[q];
          sim = fmaf(a.x, t4.x, fmaf(a.y, t4.y, fmaf(a.z, t4.z, fmaf(a.w, t4.w, sim))));
        }
      } else {
        const float* spx = (const float*)sp4;
        const float* tp  = td + (size_t)b * CD * NN + j;
#pragma unroll 8
        for (int c2 = 0; c2 < CD; ++c2) sim = fmaf(spx[c2], tp[(size_t)c2 * NN], sim);
      }
      float aj;
      if (addj) {
        aj = addj[(size_t)b * NN + j];
      } else {
        float l0 = tml[(size_t)b * 2 * NN + j];
        float l1 = tml[(size_t)b * 2 * NN + NN + j];
        float x  = l1 - l0;
        float sp = fmaxf(x, 0.0f) + log1pf(expf(-fabsf(x)));
        aj = fmaxf(-sp, -20.0f) - 0.1f * tu[(size_t)b * NN + j];
      }
      float sco = sim - sqrtf(d2) + aj;
      list[w][e].y = __float_as_int(sco);
      mloc = fmaxf(mloc, sco);
    }
#pragma unroll
    for (int off = 32; off; off >>= 1) mloc = fmaxf(mloc, __shfl_xor(mloc, off));
    const float m = mloc;

    const float C1 = (1.0f / 0.07f) * 1.44269504089f;   // log2(e)/TEMP
    float zl = 0.0f, evu = 0.0f, evm = 0.0f;
    for (int e = lane; e < na; e += 64) {
      float u  = (__int_as_float(list[w][e].y) - m) * C1;
      float ev = exp2f(u);
      list[w][e].y = __float_as_int(ev);
      zl  += ev;
      evu  = fmaf(ev, u, evu);
      evm  = fmaxf(evm, ev);
    }
#pragma unroll
    for (int off = 32; off; off >>= 1) {
      zl  += __shfl_xor(zl, off);
      evu += __shfl_xor(evu, off);
      evm  = fmaxf(evm, __shfl_xor(evm, off));
    }
    const float Z = zl, invZ = 1.0f / zl;

    // drain zero-fill stores before scattering into the same lines
    __builtin_amdgcn_s_waitcnt(0x0F70);   // vmcnt(0)

    const float STEP = 2.0f / 15.0f;
    float ex0 = 0.f, ex1 = 0.f, ex2 = 0.f;
    for (int e = lane; e < na; e += 64) {
      float p = __int_as_float(list[w][e].y) * invZ;
      int j = list[w][e].x;
      oprob[(size_t)row * NN + j] = p;
      float pz = -1.0f + STEP * (float)(j >> 8);
      float py = -1.0f + STEP * (float)((j >> 4) & 15);
      float px = -1.0f + STEP * (float)(j & 15);
      ex0 = fmaf(p, pz, ex0); ex1 = fmaf(p, py, ex1); ex2 = fmaf(p, px, ex2);
    }
#pragma unroll
    for (int off = 32; off; off >>= 1) {
      ex0 += __shfl_xor(ex0, off);
      ex1 += __shfl_xor(ex1, off);
      ex2 += __shfl_xor(ex2, off);
    }

    if (lane == 0) {
      const float LN2 = 0.69314718056f;
      float ent = LN2 * (log2f(Z) - evu * invZ);
      float tz = -1.0f + STEP * (float)(i >> 8);
      float ty = -1.0f + STEP * (float)((i >> 4) & 15);
      float tx = -1.0f + STEP * (float)(i & 15);
      size_t r3 = (size_t)row * 3;
      oexp[r3 + 0] = ex0; oexp[r3 + 1] = ex1; oexp[r3 + 2] = ex2;
      osrc[r3 + 0] = tz;  osrc[r3 + 1] = ty;  osrc[r3 + 2] = tx;
      size_t db = (size_t)b * 3 * NN;
      odisp[db + 0 * NN + i] = ex0 - tz;
      odisp[db + 1 * NN + i] = ex1 - ty;
      odisp[db + 2 * NN + i] = ex2 - tx;
      float ls0 = sml[(size_t)b * 2 * NN + i];
      float ls1 = sml[(size_t)b * 2 * NN + NN + i];
      float smv = 1.0f / (1.0f + expf(ls1 - ls0));
      oconf[(size_t)b * NN + i] = (evm * invZ) * smv;
      oent[(size_t)b * NN + i]  = ent;
    }
  }
}

extern "C" void kernel_launch(void* const* d_in, const int* in_sizes, int n_in,
                              void* d_out, int out_size, void* d_ws, size_t ws_size,
                              hipStream_t stream) {
  const float* sc  = (const float*)d_in[0];
  const float* tc  = (const float*)d_in[1];
  const float* sd  = (const float*)d_in[2];
  const float* td  = (const float*)d_in[3];
  const float* sml = (const float*)d_in[4];
  const float* tml = (const float*)d_in[5];
  const float* tu  = (const float*)d_in[7];
  // src_unc (d_in[6]) cancels in the row softmax -> unused

  float* out   = (float*)d_out;
  float* oexp  = out;
  float* odisp = oexp  + (size_t)BATCH * NN * 3;
  float* oprob = odisp + (size_t)BATCH * NN * 3;
  float* oconf = oprob + (size_t)BATCH * NN * NN;
  float* oent  = oconf + (size_t)BATCH * NN;
  float* osrc  = oent  + (size_t)BATCH * NN;

  size_t need = ((size_t)2 * BATCH * NN * CD + (size_t)BATCH * NN) * sizeof(float)
              + BATCH * sizeof(int);
  float* tdT = nullptr; float* sdT = nullptr; float* adj = nullptr; int* gcnt = nullptr;
  if (ws_size >= need) {
    tdT  = (float*)d_ws;
    sdT  = tdT + (size_t)BATCH * NN * CD;
    adj  = sdT + (size_t)BATCH * NN * CD;
    gcnt = (int*)(adj + (size_t)BATCH * NN);
    prep_all<<<256 + 32, 256, 0, stream>>>(td, sd, tml, tu, tdT, sdT, adj, gcnt);
  }
  matcher_main<<<NBLK, 256, 0, stream>>>(sc, tc, sd, td, tdT, sdT, adj, tml, tu, sml, gcnt,
                                         oexp, odisp, oprob, oconf, oent, osrc);
}

// Round 6
// 201.662 us; speedup vs baseline: 1.2694x; 1.2694x over previous
//
#include <hip/hip_runtime.h>
#include <math.h>
#include <stddef.h>

#define NN    4096
#define BATCH 2
#define CD    64
#define KSEL  24
#define RAD2  0.2025f     // 0.45^2
#define NBINS 256
#define KBASE 1888        // (118<<4): d2 in [2^-9, 2^7) keyed by float bits>>19
#define CCAP  128
#define LCAP  255         // fits uint8 index (+1 encoding)

typedef float f4v __attribute__((ext_vector_type(4)));

__device__ __forceinline__ int d2key(unsigned bits) {
  int k = (int)(bits >> 19) - KBASE;
  return k < 0 ? 0 : (k > NBINS - 1 ? NBINS - 1 : k);
}

// ---- prep: transpose td & sd to (B,N,C); addj = clamp(log tgt_match,-20) - 0.1*tu ----
__global__ __launch_bounds__(256)
void prep_all(const float* __restrict__ td, const float* __restrict__ sd,
              const float* __restrict__ tml, const float* __restrict__ tu,
              float* __restrict__ tdT, float* __restrict__ sdT,
              float* __restrict__ addj) {
  __shared__ float tile[64][65];
  int blk = blockIdx.x;
  if (blk < 256) {
    const float* src = (blk < 128) ? td  : sd;
    float*       dst = (blk < 128) ? tdT : sdT;
    int lb = blk & 127;
    int b  = lb >> 6;
    int j0 = (lb & 63) << 6;
    int jl = threadIdx.x & 63;
    int cq = threadIdx.x >> 6;
    const float* srcp = src + (size_t)b * CD * NN;
#pragma unroll
    for (int r = 0; r < 16; ++r) {
      int c = r * 4 + cq;
      tile[c][jl] = srcp[(size_t)c * NN + j0 + jl];
    }
    __syncthreads();
    float* dstp = dst + (size_t)b * NN * CD;
#pragma unroll
    for (int r = 0; r < 16; ++r) {
      int j = r * 4 + cq;
      dstp[(size_t)(j0 + j) * CD + jl] = tile[jl][j];
    }
  } else {
    int idx = (blk - 256) * 256 + threadIdx.x;
    if (idx < BATCH * NN) {
      int b = idx >> 12, j = idx & (NN - 1);
      float l0 = tml[(size_t)b * 2 * NN + j];
      float l1 = tml[(size_t)b * 2 * NN + NN + j];
      float x  = l1 - l0;
      float sp = fmaxf(x, 0.0f) + log1pf(expf(-fabsf(x)));
      addj[idx] = fmaxf(-sp, -20.0f) - 0.1f * tu[idx];
    }
  }
}

// ---- main: one block (256 thr) per row; single-pass NT row write; 8 blocks/CU ----
__global__ __launch_bounds__(256, 8)
void matcher_main(const float* __restrict__ sc, const float* __restrict__ tc,
                  const float* __restrict__ sd, const float* __restrict__ td,
                  const float* __restrict__ tdT, const float* __restrict__ sdT,
                  const float* __restrict__ addj,
                  const float* __restrict__ tml, const float* __restrict__ tu,
                  const float* __restrict__ sml,
                  float* __restrict__ oexp, float* __restrict__ odisp,
                  float* __restrict__ oprob, float* __restrict__ oconf,
                  float* __restrict__ oent, float* __restrict__ osrc) {
  __shared__ __align__(16) unsigned idxb32[NN / 4];   // 4 KB: per-j byte -> list idx+1
  __shared__ __align__(16) int      hist[NBINS];
  __shared__ __align__(16) float4   sdp4[CD / 4];
  __shared__ float    pv[LCAP + 1];
  __shared__ int2     jl[LCAP];
  __shared__ unsigned cand[CCAP];
  __shared__ float    red[4][8];
  __shared__ float    fbuf[4];
  __shared__ int      wtot[4];
  __shared__ int      candn, lcount, sBin, sBelow;
  __shared__ float    sD24;

  const int tid  = threadIdx.x;
  const int w    = tid >> 6;
  const int lane = tid & 63;
  const int row  = blockIdx.x;
  const int b    = row >> 12;
  const int i    = row & (NN - 1);

  // ---- init ----
  if (tid < 64) ((int4*)hist)[tid] = make_int4(0, 0, 0, 0);
#pragma unroll
  for (int q = 0; q < 4; ++q) idxb32[(q << 8) + tid] = 0u;
  if (sdT) { if (tid < 16) sdp4[tid] = ((const float4*)(sdT + ((size_t)b * NN + i) * CD))[tid]; }
  else     { if (tid < 64) ((float*)sdp4)[tid] = sd[(size_t)b * CD * NN + (size_t)tid * NN + i]; }
  if (tid == 0) { candn = 0; lcount = 0; sBin = -1; sBelow = 0; }

  const float* scb = sc + (size_t)b * 3 * NN;
  const float s0 = scb[i], s1 = scb[NN + i], s2 = scb[2 * NN + i];
  const float4* tcx = (const float4*)(tc + (size_t)b * 3 * NN);
  const float4* tcy = tcx + NN / 4;
  const float4* tcz = tcy + NN / 4;
  __syncthreads();

  // ---- phase 1: d2 for 16 j's per thread (regs) + full-range log histogram ----
  unsigned d2b[16];
#pragma unroll
  for (int k = 0; k < 4; ++k) {
    int g = (k << 8) + tid;                  // float4-group index in [0,1024)
    float4 X = tcx[g], Y = tcy[g], Z = tcz[g];
    float xs[4] = {X.x, X.y, X.z, X.w};
    float ys[4] = {Y.x, Y.y, Y.z, Y.w};
    float zs[4] = {Z.x, Z.y, Z.z, Z.w};
#pragma unroll
    for (int r = 0; r < 4; ++r) {
      float dx = xs[r] - s0, dy = ys[r] - s1, dz = zs[r] - s2;
      float d2 = fmaxf(__fmaf_rn(dx, dx, __fmaf_rn(dy, dy, dz * dz)), 1e-12f);
      unsigned bits = __float_as_uint(d2);
      d2b[(k << 2) + r] = bits;
      atomicAdd(&hist[d2key(bits)], 1);
    }
  }
  __syncthreads();

  // ---- phase 2: 256-bin block scan -> bin containing 24th smallest ----
  {
    int h = hist[tid];
    int inc = h;
#pragma unroll
    for (int off = 1; off < 64; off <<= 1) {
      int t = __shfl_up(inc, off);
      if (lane >= off) inc += t;
    }
    if (lane == 63) wtot[w] = inc;
    __syncthreads();
    int wb = 0;
#pragma unroll
    for (int ww = 0; ww < 4; ++ww) wb += (ww < w) ? wtot[ww] : 0;
    int below = wb + inc - h;
    if (below < KSEL && below + h >= KSEL) {
      sBin = tid; sBelow = below;
      sD24 = __uint_as_float((unsigned)(tid + KBASE + 1) << 19);  // default: bin upper edge
    }
    __syncthreads();
  }
  const int Bs = sBin, cb = sBelow;

  // ---- phase 3: boundary-bin candidates + exact rank -> d24 ----
#pragma unroll
  for (int m = 0; m < 16; ++m) {
    if (d2key(d2b[m]) == Bs) {
      int c = atomicAdd(&candn, 1);
      if (c < CCAP) cand[c] = d2b[m];
    }
  }
  __syncthreads();
  {
    int nc = candn < CCAP ? candn : CCAP;
    int Krem = KSEL - cb;
    if (tid < nc) {
      unsigned v = cand[tid];
      int lt = 0, le = 0;
      for (int m = 0; m < nc; ++m) { unsigned u = cand[m]; lt += (u < v); le += (u <= v); }
      if (lt < Krem && le >= Krem) sD24 = __uint_as_float(v);
    }
    __syncthreads();
  }
  const unsigned thrb = __float_as_uint(fmaxf(sD24, RAD2));

  // ---- phase 4: compact allowed; record byte index per j ----
#pragma unroll
  for (int m = 0; m < 16; ++m) {
    if (d2b[m] <= thrb) {
      int idx = atomicAdd(&lcount, 1);
      if (idx < LCAP) {
        int j = ((m >> 2) << 10) + (tid << 2) + (m & 3);   // j = 4*(k*256+tid)+r
        ((unsigned char*)idxb32)[j] = (unsigned char)(idx + 1);
        jl[idx] = make_int2(j, (int)d2b[m]);
      }
    }
  }
  __syncthreads();
  const int na = lcount < LCAP ? lcount : LCAP;

  // ---- phase 5: scores + softmax weights (threads 0..na-1 active) ----
  const float* tdb = tdT ? tdT + (size_t)b * NN * CD : nullptr;
  float sco = -1e30f;
  int   jme = 0;
  if (tid < na) {
    int2 en = jl[tid];
    jme = en.x;
    float d2 = __uint_as_float((unsigned)en.y);
    float a0 = 0.f, a1 = 0.f, a2 = 0.f, a3 = 0.f;
    if (tdb) {
      const float4* trow = (const float4*)(tdb + (size_t)jme * CD);
#pragma unroll
      for (int q = 0; q < CD / 4; q += 4) {
        float4 x0 = sdp4[q],     t0 = trow[q];
        float4 x1 = sdp4[q + 1], t1 = trow[q + 1];
        float4 x2 = sdp4[q + 2], t2 = trow[q + 2];
        float4 x3 = sdp4[q + 3], t3 = trow[q + 3];
        a0 = fmaf(x0.x, t0.x, fmaf(x0.y, t0.y, fmaf(x0.z, t0.z, fmaf(x0.w, t0.w, a0))));
        a1 = fmaf(x1.x, t1.x, fmaf(x1.y, t1.y, fmaf(x1.z, t1.z, fmaf(x1.w, t1.w, a1))));
        a2 = fmaf(x2.x, t2.x, fmaf(x2.y, t2.y, fmaf(x2.z, t2.z, fmaf(x2.w, t2.w, a2))));
        a3 = fmaf(x3.x, t3.x, fmaf(x3.y, t3.y, fmaf(x3.z, t3.z, fmaf(x3.w, t3.w, a3))));
      }
    } else {
      const float* spx = (const float*)sdp4;
      const float* tp  = td + (size_t)b * CD * NN + jme;
#pragma unroll 8
      for (int c2 = 0; c2 < CD; ++c2) a0 = fmaf(spx[c2], tp[(size_t)c2 * NN], a0);
    }
    float sim = (a0 + a1) + (a2 + a3);
    float aj;
    if (addj) {
      aj = addj[(size_t)b * NN + jme];
    } else {
      float l0 = tml[(size_t)b * 2 * NN + jme];
      float l1 = tml[(size_t)b * 2 * NN + NN + jme];
      float x  = l1 - l0;
      float sp = fmaxf(x, 0.0f) + log1pf(expf(-fabsf(x)));
      aj = fmaxf(-sp, -20.0f) - 0.1f * tu[(size_t)b * NN + jme];
    }
    sco = sim - sqrtf(d2) + aj;
  }
  // block max
  float mv = sco;
#pragma unroll
  for (int off = 32; off; off >>= 1) mv = fmaxf(mv, __shfl_xor(mv, off));
  if (lane == 0) fbuf[w] = mv;
  __syncthreads();
  mv = fmaxf(fmaxf(fbuf[0], fbuf[1]), fmaxf(fbuf[2], fbuf[3]));
  __syncthreads();                       // protect fbuf reuse
  const float C1 = (1.0f / 0.07f) * 1.44269504089f;   // log2(e)/TEMP
  float ev = 0.0f;
  if (tid < na) ev = exp2f((sco - mv) * C1);
  float zs = ev;
#pragma unroll
  for (int off = 32; off; off >>= 1) zs += __shfl_xor(zs, off);
  if (lane == 0) fbuf[w] = zs;
  __syncthreads();
  const float Z = fbuf[0] + fbuf[1] + fbuf[2] + fbuf[3];
  const float invZ = 1.0f / Z;
  if (tid < na) pv[tid] = ev * invZ;
  __syncthreads();

  // ---- phase 6: single-pass coalesced NT row write + fused epilogue accumulation ----
  const float STEP = 2.0f / 15.0f;
  float ex0 = 0.f, ex1 = 0.f, ex2 = 0.f, pent = 0.f, pmax = 0.f;
  f4v* prow4 = (f4v*)(oprob + (size_t)row * NN);
#pragma unroll
  for (int q = 0; q < 4; ++q) {
    int c = (q << 8) + tid;
    unsigned pk = idxb32[c];
    f4v v;
#pragma unroll
    for (int r = 0; r < 4; ++r) {
      unsigned u8 = (pk >> (8 * r)) & 0xFFu;
      float p = 0.0f;
      if (u8) {
        p = pv[u8 - 1];
        int j = (c << 2) + r;
        float pz = -1.0f + STEP * (float)(j >> 8);
        float py = -1.0f + STEP * (float)((j >> 4) & 15);
        float px = -1.0f + STEP * (float)(j & 15);
        ex0 = fmaf(p, pz, ex0); ex1 = fmaf(p, py, ex1); ex2 = fmaf(p, px, ex2);
        pent = fmaf(p, logf(fmaxf(p, 1e-12f)), pent);
        pmax = fmaxf(pmax, p);
      }
      v[r] = p;
    }
    __builtin_nontemporal_store(v, &prow4[c]);
  }
  // combined 5-value block reduction
#pragma unroll
  for (int off = 32; off; off >>= 1) {
    ex0 += __shfl_xor(ex0, off);
    ex1 += __shfl_xor(ex1, off);
    ex2 += __shfl_xor(ex2, off);
    pent += __shfl_xor(pent, off);
    pmax = fmaxf(pmax, __shfl_xor(pmax, off));
  }
  if (lane == 0) {
    red[w][0] = ex0; red[w][1] = ex1; red[w][2] = ex2; red[w][3] = pent; red[w][4] = pmax;
  }
  __syncthreads();
  if (tid == 0) {
    float e0 = 0.f, e1 = 0.f, e2 = 0.f, pe = 0.f, pm = 0.f;
#pragma unroll
    for (int ww = 0; ww < 4; ++ww) {
      e0 += red[ww][0]; e1 += red[ww][1]; e2 += red[ww][2]; pe += red[ww][3];
      pm = fmaxf(pm, red[ww][4]);
    }
    float tz = -1.0f + STEP * (float)(i >> 8);
    float ty = -1.0f + STEP * (float)((i >> 4) & 15);
    float tx = -1.0f + STEP * (float)(i & 15);
    size_t r3 = (size_t)row * 3;
    oexp[r3 + 0] = e0; oexp[r3 + 1] = e1; oexp[r3 + 2] = e2;
    osrc[r3 + 0] = tz; osrc[r3 + 1] = ty; osrc[r3 + 2] = tx;
    size_t db = (size_t)b * 3 * NN;
    odisp[db + 0 * NN + i] = e0 - tz;
    odisp[db + 1 * NN + i] = e1 - ty;
    odisp[db + 2 * NN + i] = e2 - tx;
    float ls0 = sml[(size_t)b * 2 * NN + i];
    float ls1 = sml[(size_t)b * 2 * NN + NN + i];
    float smv = 1.0f / (1.0f + expf(ls1 - ls0));
    oconf[(size_t)b * NN + i] = pm * smv;
    oent[(size_t)b * NN + i]  = -pe;
  }
}

extern "C" void kernel_launch(void* const* d_in, const int* in_sizes, int n_in,
                              void* d_out, int out_size, void* d_ws, size_t ws_size,
                              hipStream_t stream) {
  const float* sc  = (const float*)d_in[0];
  const float* tc  = (const float*)d_in[1];
  const float* sd  = (const float*)d_in[2];
  const float* td  = (const float*)d_in[3];
  const float* sml = (const float*)d_in[4];
  const float* tml = (const float*)d_in[5];
  const float* tu  = (const float*)d_in[7];
  // src_unc (d_in[6]) cancels in the row softmax -> unused

  float* out   = (float*)d_out;
  float* oexp  = out;
  float* odisp = oexp  + (size_t)BATCH * NN * 3;
  float* oprob = odisp + (size_t)BATCH * NN * 3;
  float* oconf = oprob + (size_t)BATCH * NN * NN;
  float* oent  = oconf + (size_t)BATCH * NN;
  float* osrc  = oent  + (size_t)BATCH * NN;

  size_t need = ((size_t)2 * BATCH * NN * CD + (size_t)BATCH * NN) * sizeof(float);
  float* tdT = nullptr; float* sdT = nullptr; float* adj = nullptr;
  if (ws_size >= need) {
    tdT = (float*)d_ws;
    sdT = tdT + (size_t)BATCH * NN * CD;
    adj = sdT + (size_t)BATCH * NN * CD;
    prep_all<<<256 + 32, 256, 0, stream>>>(td, sd, tml, tu, tdT, sdT, adj);
  }
  matcher_main<<<BATCH * NN, 256, 0, stream>>>(sc, tc, sd, td, tdT, sdT, adj,
                                               tml, tu, sml,
                                               oexp, odisp, oprob, oconf, oent, osrc);
}